// Round 4
// baseline (1383.892 us; speedup 1.0000x reference)
//
#include <hip/hip_runtime.h>
#include <stdint.h>

#define NN 100000      // nodes
#define NE 1600000     // edges
#define MAXDEG 64      // Poisson(16) tail beyond 64 ~ 1e-19/node: safe cap

// ---- build per-dst neighbor buckets ----
__global__ __launch_bounds__(256) void build_buckets(const int* __restrict__ src,
                                                     const int* __restrict__ dst,
                                                     int* __restrict__ cnt,
                                                     int* __restrict__ buck) {
  int e = blockIdx.x * 256 + threadIdx.x;
  if (e >= NE) return;
  int d = dst[e];
  int p = atomicAdd(&cnt[d], 1);
  if (p < MAXDEG) buck[d * MAXDEG + p] = src[e];
}

// ---- fused SAGE layer: out = relu?( mean_agg(xin) @ Wl + b + xin @ Wr ) ----
// All tensors float32. Block = 256 thr (4 waves), 64 nodes per block.
// Phase 1: each wave aggregates 16 nodes (lane covers 2 features) -> LDS fp32.
// Phase 2: VALU GEMM: thread = (node-group, out-col); LDS rows broadcast across
//          the col-threads of a group; W read k-major, coalesced across cols.
template <int M, bool RELU>
__global__ __launch_bounds__(256) void sage_layer(const float* __restrict__ xin,
                                                  const int* __restrict__ cnt,
                                                  const int* __restrict__ buck,
                                                  const float* __restrict__ Wl,
                                                  const float* __restrict__ Wr,
                                                  const float* __restrict__ bias,
                                                  float* __restrict__ out) {
  __shared__ float sAgg[64][128];   // 32 KB — mean of neighbor features
  __shared__ float sX[64][128];     // 32 KB — own features

  const int t = threadIdx.x;
  const int lane = t & 63;
  const int w = t >> 6;
  const int node0 = blockIdx.x * 64;

  // ---- phase 1: aggregate + stage own row (every LDS cell written, incl. tail) ----
  for (int i = 0; i < 16; i++) {
    int local = w * 16 + i;
    int node = node0 + local;
    float a0 = 0.f, a1 = 0.f, x0 = 0.f, x1 = 0.f;
    if (node < NN) {
      int deg = cnt[node];
      int dcl = min(deg, MAXDEG);
      const int4* bb = (const int4*)(buck + (size_t)node * MAXDEG);
      for (int p = 0; p < dcl; p += 4) {
        int4 s = bb[p >> 2];
        int rem = dcl - p;                     // wave-uniform branches
        { float2 v = *(const float2*)(xin + (size_t)s.x * 128 + 2 * lane); a0 += v.x; a1 += v.y; }
        if (rem > 1) { float2 v = *(const float2*)(xin + (size_t)s.y * 128 + 2 * lane); a0 += v.x; a1 += v.y; }
        if (rem > 2) { float2 v = *(const float2*)(xin + (size_t)s.z * 128 + 2 * lane); a0 += v.x; a1 += v.y; }
        if (rem > 3) { float2 v = *(const float2*)(xin + (size_t)s.w * 128 + 2 * lane); a0 += v.x; a1 += v.y; }
      }
      float inv = 1.f / (float)(deg > 1 ? deg : 1);
      a0 *= inv; a1 *= inv;
      float2 vx = *(const float2*)(xin + (size_t)node * 128 + 2 * lane);
      x0 = vx.x; x1 = vx.y;
    }
    *(float2*)&sAgg[local][2 * lane] = make_float2(a0, a1);
    *(float2*)&sX[local][2 * lane]   = make_float2(x0, x1);
  }
  __syncthreads();

  // ---- phase 2: [sAgg | sX] (64x256 fp32) @ [Wl ; Wr] (256xM fp32) ----
  constexpr int NPT = 64 / (256 / M);    // nodes per thread: M=128 -> 32, M=64 -> 16
  const int col = t & (M - 1);
  const int ng = t / M;                  // node-group
  const int nbase = ng * NPT;

  float acc[NPT];
  float bcol = bias[col];
#pragma unroll
  for (int i = 0; i < NPT; i++) acc[i] = bcol;

  for (int k0 = 0; k0 < 256; k0 += 8) {
    const float* Wsrc = (k0 < 128) ? (Wl + (size_t)k0 * M + col)
                                   : (Wr + (size_t)(k0 - 128) * M + col);
    float w8[8];
#pragma unroll
    for (int j = 0; j < 8; j++) w8[j] = Wsrc[(size_t)j * M];
    const float* Sb = (k0 < 128) ? &sAgg[0][0] : &sX[0][0];
    const int kb = k0 & 127;
#pragma unroll
    for (int i = 0; i < NPT; i++) {
      const float4* Sr = (const float4*)(Sb + (size_t)(nbase + i) * 128 + kb);
      float4 u0 = Sr[0], u1 = Sr[1];
      acc[i] += u0.x * w8[0] + u0.y * w8[1] + u0.z * w8[2] + u0.w * w8[3]
              + u1.x * w8[4] + u1.y * w8[5] + u1.z * w8[6] + u1.w * w8[7];
    }
  }

#pragma unroll
  for (int i = 0; i < NPT; i++) {
    int node = node0 + nbase + i;
    if (node < NN) {
      float v = acc[i];
      if (RELU) v = fmaxf(v, 0.f);
      out[(size_t)node * M + col] = v;
    }
  }
}

extern "C" void kernel_launch(void* const* d_in, const int* in_sizes, int n_in,
                              void* d_out, int out_size, void* d_ws, size_t ws_size,
                              hipStream_t stream) {
  const float* x   = (const float*)d_in[0];
  const int*   ei  = (const int*)d_in[1];
  const float* W1l = (const float*)d_in[2];
  const float* b1  = (const float*)d_in[3];
  const float* W1r = (const float*)d_in[4];
  const float* W2l = (const float*)d_in[5];
  const float* b2  = (const float*)d_in[6];
  const float* W2r = (const float*)d_in[7];
  float* out = (float*)d_out;

  // workspace: cnt (padded to 512KB) | buck 25.6MB | h 51.2MB  => 77.3MB
  char* ws = (char*)d_ws;
  int* cnt  = (int*)ws;
  int* buck = (int*)(ws + (512 << 10));
  float* h  = (float*)(ws + (512 << 10) + (size_t)NN * MAXDEG * 4);

  const int* src = ei;        // edge_index[0]
  const int* dst = ei + NE;   // edge_index[1]

  hipMemsetAsync(cnt, 0, (size_t)NN * 4, stream);
  build_buckets<<<(NE + 255) / 256, 256, 0, stream>>>(src, dst, cnt, buck);

  sage_layer<128, true><<<(NN + 63) / 64, 256, 0, stream>>>(x, cnt, buck, W1l, W1r, b1, h);
  sage_layer<64, false><<<(NN + 63) / 64, 256, 0, stream>>>(h, cnt, buck, W2l, W2r, b2, out);
}

// Round 5
// 552.718 us; speedup vs baseline: 2.5038x; 2.5038x over previous
//
#include <hip/hip_runtime.h>
#include <stdint.h>

#define NN 100000      // nodes
#define NE 1600000     // edges
#define MAXDEG 64      // Poisson(16): P(deg>64) ~ 1e-19, safe cap

typedef __attribute__((ext_vector_type(8))) short short8;
typedef __attribute__((ext_vector_type(4))) float f32x4;

__device__ __forceinline__ float bflo(unsigned v) { return __uint_as_float(v << 16); }
__device__ __forceinline__ float bfhi(unsigned v) { return __uint_as_float(v & 0xffff0000u); }
__device__ __forceinline__ unsigned short f2bf(float f) {   // round-to-nearest-even
  unsigned u = __float_as_uint(f);
  u += 0x7fff + ((u >> 16) & 1);
  return (unsigned short)(u >> 16);
}
__device__ __forceinline__ void store_out(unsigned short* p, float v) { *p = f2bf(v); }
__device__ __forceinline__ void store_out(float* p, float v) { *p = v; }

// ---- build per-dst neighbor buckets ----
__global__ __launch_bounds__(256) void build_buckets(const int* __restrict__ src,
                                                     const int* __restrict__ dst,
                                                     int* __restrict__ cnt,
                                                     int* __restrict__ buck) {
  int e = blockIdx.x * 256 + threadIdx.x;
  if (e >= NE) return;
  int d = dst[e];
  int p = atomicAdd(&cnt[d], 1);
  if (p < MAXDEG) buck[d * MAXDEG + p] = src[e];
}

// ---- f32 -> packed bf16x2 ----
__global__ __launch_bounds__(256) void to_bf16(const float* __restrict__ x,
                                               unsigned* __restrict__ xb) {
  int i = blockIdx.x * 256 + threadIdx.x;     // over N*64 (2 feats per thread)
  if (i >= NN * 64) return;
  float2 v = ((const float2*)x)[i];
  xb[i] = ((unsigned)f2bf(v.y) << 16) | f2bf(v.x);
}

// ---- one-time W transpose -> k-major bf16: WT[m][k], k = [Wl rows | Wr rows] ----
__global__ __launch_bounds__(256) void transpose_w(const float* __restrict__ W1l,
                                                   const float* __restrict__ W1r,
                                                   const float* __restrict__ W2l,
                                                   const float* __restrict__ W2r,
                                                   unsigned short* __restrict__ WT1,
                                                   unsigned short* __restrict__ WT2) {
  int t = blockIdx.x * 256 + threadIdx.x;
  if (t < 128 * 256) {
    int m = t >> 8, k = t & 255;
    float v = (k < 128) ? W1l[k * 128 + m] : W1r[(k - 128) * 128 + m];
    WT1[t] = f2bf(v);
  } else {
    int i = t - 128 * 256;
    if (i < 64 * 256) {
      int m = i >> 8, k = i & 255;
      float v = (k < 128) ? W2l[k * 64 + m] : W2r[(k - 128) * 64 + m];
      WT2[i] = f2bf(v);
    }
  }
}

// ---- mean aggregation: one wave per node, no LDS, 8 rows in flight ----
__global__ __launch_bounds__(256) void aggregate(const unsigned* __restrict__ xb,
                                                 const int* __restrict__ cnt,
                                                 const int* __restrict__ buck,
                                                 unsigned* __restrict__ agg) {
  int wid = (blockIdx.x * 256 + threadIdx.x) >> 6;
  int lane = threadIdx.x & 63;
  if (wid >= NN) return;
  int deg = cnt[wid];
  int dcl = min(deg, MAXDEG);
  int slot = buck[(size_t)wid * MAXDEG + lane];   // whole bucket row, coalesced
  float a0 = 0.f, a1 = 0.f;
  for (int p = 0; p < dcl; p += 8) {
    int rem = dcl - p;                            // wave-uniform
    unsigned v[8];
#pragma unroll
    for (int j = 0; j < 8; j++) v[j] = 0u;
#pragma unroll
    for (int j = 0; j < 8; j++)
      if (j < rem) {
        int s = __shfl(slot, p + j, 64);
        v[j] = xb[(size_t)s * 64 + lane];         // 256B/row coalesced
      }
#pragma unroll
    for (int j = 0; j < 8; j++)
      if (j < rem) { a0 += bflo(v[j]); a1 += bfhi(v[j]); }
  }
  float inv = 1.f / (float)max(deg, 1);
  a0 *= inv; a1 *= inv;
  agg[(size_t)wid * 64 + lane] = ((unsigned)f2bf(a1) << 16) | f2bf(a0);
}

// ---- MFMA GEMM: out = relu?( [agg|x] (64xK=256) @ W (256xM) + b ) ----
// 256 thr = 4 waves; 64 nodes/block; A staged in LDS (34KB -> 4 blocks/CU);
// B fragments read directly from k-major WT in global (L1/L2-resident).
template <int M, bool RELU, typename OutT>
__global__ __launch_bounds__(256) void sage_gemm(const unsigned* __restrict__ agg,
                                                 const unsigned* __restrict__ xb,
                                                 const unsigned short* __restrict__ WT,
                                                 const float* __restrict__ bias,
                                                 OutT* __restrict__ out) {
  constexpr int LDA = 264;                       // +8 bf16 pad, keeps 16B align
  __shared__ unsigned short sA[64][LDA];

  const int t = threadIdx.x;
  const int node0 = blockIdx.x * 64;

  // stage A: row = [agg(128bf16)=16 uint4 | x(128bf16)=16 uint4]
  for (int i = t; i < 64 * 32; i += 256) {
    int row = i >> 5, c = i & 31;
    int node = node0 + row;
    uint4 v = {0u, 0u, 0u, 0u};
    if (node < NN)
      v = (c < 16) ? ((const uint4*)(agg + (size_t)node * 64))[c]
                   : ((const uint4*)(xb + (size_t)node * 64))[c - 16];
    *(uint4*)&sA[row][c * 8] = v;
  }
  __syncthreads();

  const int lane = t & 63;
  const int wv = t >> 6;        // 16-node sub-tile per wave
  const int m = lane & 15;
  const int q = lane >> 4;

  f32x4 acc[M / 16];
#pragma unroll
  for (int c = 0; c < M / 16; c++) acc[c] = {0.f, 0.f, 0.f, 0.f};

#pragma unroll
  for (int ks = 0; ks < 8; ks++) {
    // A frag: A[m][q*8+j]
    short8 a = *(const short8*)&sA[wv * 16 + m][ks * 32 + q * 8];
#pragma unroll
    for (int c = 0; c < M / 16; c++) {
      // B frag: B[k=q*8+j][n=c*16+m] = WT[n][k], contiguous 16B in k
      short8 b = *(const short8*)(WT + (size_t)(c * 16 + m) * 256 + ks * 32 + q * 8);
      acc[c] = __builtin_amdgcn_mfma_f32_16x16x32_bf16(a, b, acc[c], 0, 0, 0);
    }
  }

  // epilogue: D[row=q*4+r][col=m]
#pragma unroll
  for (int c = 0; c < M / 16; c++) {
    int col = c * 16 + m;
    float bc = bias[col];
#pragma unroll
    for (int r = 0; r < 4; r++) {
      int node = node0 + wv * 16 + q * 4 + r;
      if (node < NN) {
        float v = acc[c][r] + bc;
        if (RELU) v = fmaxf(v, 0.f);
        store_out(&out[(size_t)node * M + col], v);
      }
    }
  }
}

extern "C" void kernel_launch(void* const* d_in, const int* in_sizes, int n_in,
                              void* d_out, int out_size, void* d_ws, size_t ws_size,
                              hipStream_t stream) {
  const float* x   = (const float*)d_in[0];
  const int*   ei  = (const int*)d_in[1];
  const float* W1l = (const float*)d_in[2];
  const float* b1  = (const float*)d_in[3];
  const float* W1r = (const float*)d_in[4];
  const float* W2l = (const float*)d_in[5];
  const float* b2  = (const float*)d_in[6];
  const float* W2r = (const float*)d_in[7];
  float* out = (float*)d_out;

  // ws: cnt 0.5MB | buck 25.6MB | xbf 12.8MB | agg 12.8MB | h 12.8MB | WT1 64KB | WT2 32KB
  char* ws = (char*)d_ws;
  int* cnt  = (int*)ws;                                   ws += (512 << 10);
  int* buck = (int*)ws;                                   ws += (size_t)NN * MAXDEG * 4;
  unsigned* xbf = (unsigned*)ws;                          ws += (size_t)NN * 64 * 4;
  unsigned* aggb = (unsigned*)ws;                         ws += (size_t)NN * 64 * 4;
  unsigned* hb = (unsigned*)ws;                           ws += (size_t)NN * 64 * 4;
  unsigned short* WT1 = (unsigned short*)ws;              ws += 128 * 256 * 2;
  unsigned short* WT2 = (unsigned short*)ws;              ws += 64 * 256 * 2;

  const int* src = ei;        // edge_index[0]
  const int* dst = ei + NE;   // edge_index[1]

  hipMemsetAsync(cnt, 0, (size_t)NN * 4, stream);
  build_buckets<<<(NE + 255) / 256, 256, 0, stream>>>(src, dst, cnt, buck);
  to_bf16<<<(NN * 64 + 255) / 256, 256, 0, stream>>>(x, xbf);
  transpose_w<<<192, 256, 0, stream>>>(W1l, W1r, W2l, W2r, WT1, WT2);

  // layer 1: h = relu([mean|x] @ [W1l;W1r] + b1), bf16
  aggregate<<<(NN * 64 + 255) / 256, 256, 0, stream>>>(xbf, cnt, buck, aggb);
  sage_gemm<128, true, unsigned short><<<(NN + 63) / 64, 256, 0, stream>>>(
      aggb, xbf, WT1, b1, (unsigned short*)hb);

  // layer 2: out = [mean|h] @ [W2l;W2r] + b2, f32
  aggregate<<<(NN * 64 + 255) / 256, 256, 0, stream>>>(hb, cnt, buck, aggb);
  sage_gemm<64, false, float><<<(NN + 63) / 64, 256, 0, stream>>>(
      aggb, hb, WT2, b2, out);
}

// Round 6
// 540.458 us; speedup vs baseline: 2.5606x; 1.0227x over previous
//
#include <hip/hip_runtime.h>
#include <stdint.h>

#define NN 100000      // nodes
#define NE 1600000     // edges
#define MAXDEG 64      // Poisson(16): P(deg>64) ~ 1e-19, safe cap

typedef __attribute__((ext_vector_type(8))) short short8;
typedef __attribute__((ext_vector_type(4))) float f32x4;

__device__ __forceinline__ float bflo(unsigned v) { return __uint_as_float(v << 16); }
__device__ __forceinline__ float bfhi(unsigned v) { return __uint_as_float(v & 0xffff0000u); }
__device__ __forceinline__ unsigned short f2bf(float f) {   // round-to-nearest-even
  unsigned u = __float_as_uint(f);
  u += 0x7fff + ((u >> 16) & 1);
  return (unsigned short)(u >> 16);
}

// ---- build per-dst neighbor buckets: 8 edges/thread = 8 independent atomic chains ----
__global__ __launch_bounds__(256) void build_buckets(const int* __restrict__ src,
                                                     const int* __restrict__ dst,
                                                     int* __restrict__ cnt,
                                                     int* __restrict__ buck) {
  int tid = blockIdx.x * 256 + threadIdx.x;      // NE/8 = 200000 threads
  if (tid >= NE / 8) return;
  const int4* s4 = (const int4*)(src + tid * 8);
  const int4* d4 = (const int4*)(dst + tid * 8);
  int4 sa = s4[0], sb = s4[1];
  int4 da = d4[0], db = d4[1];
  int p0 = atomicAdd(&cnt[da.x], 1);
  int p1 = atomicAdd(&cnt[da.y], 1);
  int p2 = atomicAdd(&cnt[da.z], 1);
  int p3 = atomicAdd(&cnt[da.w], 1);
  int p4 = atomicAdd(&cnt[db.x], 1);
  int p5 = atomicAdd(&cnt[db.y], 1);
  int p6 = atomicAdd(&cnt[db.z], 1);
  int p7 = atomicAdd(&cnt[db.w], 1);
  if (p0 < MAXDEG) buck[da.x * MAXDEG + p0] = sa.x;
  if (p1 < MAXDEG) buck[da.y * MAXDEG + p1] = sa.y;
  if (p2 < MAXDEG) buck[da.z * MAXDEG + p2] = sa.z;
  if (p3 < MAXDEG) buck[da.w * MAXDEG + p3] = sa.w;
  if (p4 < MAXDEG) buck[db.x * MAXDEG + p4] = sb.x;
  if (p5 < MAXDEG) buck[db.y * MAXDEG + p5] = sb.y;
  if (p6 < MAXDEG) buck[db.z * MAXDEG + p6] = sb.z;
  if (p7 < MAXDEG) buck[db.w * MAXDEG + p7] = sb.w;
}

// ---- f32 -> packed bf16x2 (float4 per thread) ----
__global__ __launch_bounds__(256) void to_bf16(const float* __restrict__ x,
                                               unsigned* __restrict__ xb) {
  int i = blockIdx.x * 256 + threadIdx.x;     // over NN*32
  if (i >= NN * 32) return;
  float4 v = ((const float4*)x)[i];
  uint2 o;
  o.x = ((unsigned)f2bf(v.y) << 16) | f2bf(v.x);
  o.y = ((unsigned)f2bf(v.w) << 16) | f2bf(v.z);
  ((uint2*)xb)[i] = o;
}

// ---- one-time W transpose -> k-major bf16: WT[m][k], k = [Wl rows | Wr rows] ----
__global__ __launch_bounds__(256) void transpose_w(const float* __restrict__ W1l,
                                                   const float* __restrict__ W1r,
                                                   const float* __restrict__ W2l,
                                                   const float* __restrict__ W2r,
                                                   unsigned short* __restrict__ WT1,
                                                   unsigned short* __restrict__ WT2) {
  int t = blockIdx.x * 256 + threadIdx.x;
  if (t < 128 * 256) {
    int m = t >> 8, k = t & 255;
    float v = (k < 128) ? W1l[k * 128 + m] : W1r[(k - 128) * 128 + m];
    WT1[t] = f2bf(v);
  } else {
    int i = t - 128 * 256;
    if (i < 64 * 256) {
      int m = i >> 8, k = i & 255;
      float v = (k < 128) ? W2l[k * 64 + m] : W2r[(k - 128) * 64 + m];
      WT2[i] = f2bf(v);
    }
  }
}

// ---- mean aggregation: one wave per node, 16 rows in flight ----
__global__ __launch_bounds__(256) void aggregate(const unsigned* __restrict__ xb,
                                                 const int* __restrict__ cnt,
                                                 const int* __restrict__ buck,
                                                 unsigned* __restrict__ agg) {
  int wid = (blockIdx.x * 256 + threadIdx.x) >> 6;
  int lane = threadIdx.x & 63;
  if (wid >= NN) return;
  int deg = cnt[wid];
  int dcl = min(deg, MAXDEG);
  int slot = buck[(size_t)wid * MAXDEG + lane];   // whole bucket row, coalesced
  float a0 = 0.f, a1 = 0.f;
  for (int p = 0; p < dcl; p += 16) {
    int rem = dcl - p;                            // wave-uniform
    unsigned v[16];
#pragma unroll
    for (int j = 0; j < 16; j++)
      if (j < rem) {
        int s = __shfl(slot, p + j, 64);
        v[j] = xb[(size_t)s * 64 + lane];         // 256B/row coalesced
      }
#pragma unroll
    for (int j = 0; j < 16; j++)
      if (j < rem) { a0 += bflo(v[j]); a1 += bfhi(v[j]); }
  }
  float inv = 1.f / (float)max(deg, 1);
  a0 *= inv; a1 *= inv;
  agg[(size_t)wid * 64 + lane] = ((unsigned)f2bf(a1) << 16) | f2bf(a0);
}

// ---- MFMA GEMM: out = relu?( [agg|x] (64xK=256) @ W (256xM) + b ) ----
// 256 thr = 4 waves; 64 nodes/block; A staged in LDS; B from k-major WT (L2-hot).
// Epilogue: C-tile restaged through wave-private sA rows -> full-line uint4 stores.
template <int M, bool RELU, typename OutT>
__global__ __launch_bounds__(256) void sage_gemm(const unsigned* __restrict__ agg,
                                                 const unsigned* __restrict__ xb,
                                                 const unsigned short* __restrict__ WT,
                                                 const float* __restrict__ bias,
                                                 OutT* __restrict__ out) {
  constexpr int LDA = 264;                       // +8 bf16 pad; 528B pitch = 33x16B
  __shared__ unsigned short sA[64][LDA];

  const int t = threadIdx.x;
  const int node0 = blockIdx.x * 64;

  // stage A: row = [agg(128bf16)=16 uint4 | x(128bf16)=16 uint4]
  for (int i = t; i < 64 * 32; i += 256) {
    int row = i >> 5, c = i & 31;
    int node = node0 + row;
    uint4 v = {0u, 0u, 0u, 0u};
    if (node < NN)
      v = (c < 16) ? ((const uint4*)(agg + (size_t)node * 64))[c]
                   : ((const uint4*)(xb + (size_t)node * 64))[c - 16];
    *(uint4*)&sA[row][c * 8] = v;
  }
  __syncthreads();

  const int lane = t & 63;
  const int wv = t >> 6;        // 16-node sub-tile per wave
  const int m = lane & 15;
  const int q = lane >> 4;

  f32x4 acc[M / 16];
#pragma unroll
  for (int c = 0; c < M / 16; c++) acc[c] = {0.f, 0.f, 0.f, 0.f};

#pragma unroll
  for (int ks = 0; ks < 8; ks++) {
    short8 a = *(const short8*)&sA[wv * 16 + m][ks * 32 + q * 8];   // A[m][q*8+j]
#pragma unroll
    for (int c = 0; c < M / 16; c++) {
      // B[k=q*8+j][n=c*16+m] = WT[n][k], contiguous 16B in k
      short8 b = *(const short8*)(WT + (size_t)(c * 16 + m) * 256 + ks * 32 + q * 8);
      acc[c] = __builtin_amdgcn_mfma_f32_16x16x32_bf16(a, b, acc[c], 0, 0, 0);
    }
  }

  // ---- epilogue: stage into own wave's dead sA rows (no barrier needed:
  // rows [wv*16, wv*16+16) are only ever read by this wave, and those reads
  // completed above), then coalesced full-line copies out.
#pragma unroll
  for (int c = 0; c < M / 16; c++) {
    int col = c * 16 + m;
    float bc = bias[col];
#pragma unroll
    for (int r = 0; r < 4; r++) {
      int lr = wv * 16 + q * 4 + r;               // D[row=q*4+r][col=m]
      float v = acc[c][r] + bc;
      if (RELU) v = fmaxf(v, 0.f);
      if constexpr (sizeof(OutT) == 2) sA[lr][col] = f2bf(v);
      else ((float*)&sA[lr][0])[col] = v;
    }
  }
  // row payload = 256B both cases (128 bf16 or 64 f32) = 16 uint4 chunks
#pragma unroll
  for (int it = 0; it < 4; it++) {
    int idx = it * 64 + lane;                     // 16 rows x 16 chunks
    int rr = idx >> 4, cc = idx & 15;
    int node = node0 + wv * 16 + rr;
    if (node < NN) {
      uint4 v = *(const uint4*)((const char*)&sA[wv * 16 + rr][0] + cc * 16);
      *(uint4*)((char*)(out + (size_t)node * M) + cc * 16) = v;
    }
  }
}

extern "C" void kernel_launch(void* const* d_in, const int* in_sizes, int n_in,
                              void* d_out, int out_size, void* d_ws, size_t ws_size,
                              hipStream_t stream) {
  const float* x   = (const float*)d_in[0];
  const int*   ei  = (const int*)d_in[1];
  const float* W1l = (const float*)d_in[2];
  const float* b1  = (const float*)d_in[3];
  const float* W1r = (const float*)d_in[4];
  const float* W2l = (const float*)d_in[5];
  const float* b2  = (const float*)d_in[6];
  const float* W2r = (const float*)d_in[7];
  float* out = (float*)d_out;

  // ws: cnt 0.5MB | buck 25.6MB | xbf 12.8MB | agg 12.8MB | h 12.8MB | WT1 | WT2
  char* ws = (char*)d_ws;
  int* cnt  = (int*)ws;                                   ws += (512 << 10);
  int* buck = (int*)ws;                                   ws += (size_t)NN * MAXDEG * 4;
  unsigned* xbf = (unsigned*)ws;                          ws += (size_t)NN * 64 * 4;
  unsigned* aggb = (unsigned*)ws;                         ws += (size_t)NN * 64 * 4;
  unsigned* hb = (unsigned*)ws;                           ws += (size_t)NN * 64 * 4;
  unsigned short* WT1 = (unsigned short*)ws;              ws += 128 * 256 * 2;
  unsigned short* WT2 = (unsigned short*)ws;              ws += 64 * 256 * 2;

  const int* src = ei;        // edge_index[0]
  const int* dst = ei + NE;   // edge_index[1]

  hipMemsetAsync(cnt, 0, (size_t)NN * 4, stream);
  build_buckets<<<(NE / 8 + 255) / 256, 256, 0, stream>>>(src, dst, cnt, buck);
  to_bf16<<<(NN * 32 + 255) / 256, 256, 0, stream>>>(x, xbf);
  transpose_w<<<192, 256, 0, stream>>>(W1l, W1r, W2l, W2r, WT1, WT2);

  // layer 1: h = relu([mean|x] @ [W1l;W1r] + b1), bf16
  aggregate<<<(NN * 64 + 255) / 256, 256, 0, stream>>>(xbf, cnt, buck, aggb);
  sage_gemm<128, true, unsigned short><<<(NN + 63) / 64, 256, 0, stream>>>(
      aggb, xbf, WT1, b1, (unsigned short*)hb);

  // layer 2: out = [mean|h] @ [W2l;W2r] + b2, f32
  aggregate<<<(NN * 64 + 255) / 256, 256, 0, stream>>>(hb, cnt, buck, aggb);
  sage_gemm<64, false, float><<<(NN + 63) / 64, 256, 0, stream>>>(
      aggb, hb, WT2, b2, out);
}

// Round 7
// 481.012 us; speedup vs baseline: 2.8770x; 1.1236x over previous
//
#include <hip/hip_runtime.h>
#include <stdint.h>

#define NN 100000      // nodes
#define NE 1600000     // edges
#define MAXDEG 64      // Poisson(16): P(deg>64) ~ 1e-19, safe cap
#define NSLICE 8       // XCD count; slice = blockIdx & 7 (perf heuristic only)
#define SLICE_SZ 12500 // nodes per slice
#define CHUNK 6400     // edges per block; NE/CHUNK = 250 chunks per slice

typedef __attribute__((ext_vector_type(8))) short short8;
typedef __attribute__((ext_vector_type(4))) float f32x4;

__device__ __forceinline__ float bflo(unsigned v) { return __uint_as_float(v << 16); }
__device__ __forceinline__ float bfhi(unsigned v) { return __uint_as_float(v & 0xffff0000u); }
__device__ __forceinline__ unsigned short f2bf(float f) {   // round-to-nearest-even
  unsigned u = __float_as_uint(f);
  u += 0x7fff + ((u >> 16) & 1);
  return (unsigned short)(u >> 16);
}

// ---- XCD-sliced bucket build: per-XCD write region 3.2MB -> L2-resident,
// scatter writes merge in L2 instead of 1 line-writeback per 4B store.
__global__ __launch_bounds__(256) void build_buckets(const int* __restrict__ src,
                                                     const int* __restrict__ dst,
                                                     int* __restrict__ cnt,
                                                     int* __restrict__ buck) {
  const int slice = blockIdx.x & (NSLICE - 1);
  const int chunk = blockIdx.x >> 3;
  const int c0 = chunk * CHUNK;
  const int lo = slice * SLICE_SZ, hi = lo + SLICE_SZ;
  for (int e = c0 + (int)threadIdx.x * 4; e < c0 + CHUNK; e += 1024) {
    int4 d = *(const int4*)(dst + e);
    int4 s = *(const int4*)(src + e);
    if (d.x >= lo && d.x < hi) { int p = atomicAdd(&cnt[d.x], 1); if (p < MAXDEG) buck[d.x * MAXDEG + p] = s.x; }
    if (d.y >= lo && d.y < hi) { int p = atomicAdd(&cnt[d.y], 1); if (p < MAXDEG) buck[d.y * MAXDEG + p] = s.y; }
    if (d.z >= lo && d.z < hi) { int p = atomicAdd(&cnt[d.z], 1); if (p < MAXDEG) buck[d.z * MAXDEG + p] = s.z; }
    if (d.w >= lo && d.w < hi) { int p = atomicAdd(&cnt[d.w], 1); if (p < MAXDEG) buck[d.w * MAXDEG + p] = s.w; }
  }
}

// ---- f32 -> packed bf16x2 (float4 per thread) ----
__global__ __launch_bounds__(256) void to_bf16(const float* __restrict__ x,
                                               unsigned* __restrict__ xb) {
  int i = blockIdx.x * 256 + threadIdx.x;     // over NN*32
  if (i >= NN * 32) return;
  float4 v = ((const float4*)x)[i];
  uint2 o;
  o.x = ((unsigned)f2bf(v.y) << 16) | f2bf(v.x);
  o.y = ((unsigned)f2bf(v.w) << 16) | f2bf(v.z);
  ((uint2*)xb)[i] = o;
}

// ---- one-time W transpose -> k-major bf16: WT[m][k], k = [Wl rows | Wr rows] ----
__global__ __launch_bounds__(256) void transpose_w(const float* __restrict__ W1l,
                                                   const float* __restrict__ W1r,
                                                   const float* __restrict__ W2l,
                                                   const float* __restrict__ W2r,
                                                   unsigned short* __restrict__ WT1,
                                                   unsigned short* __restrict__ WT2) {
  int t = blockIdx.x * 256 + threadIdx.x;
  if (t < 128 * 256) {
    int m = t >> 8, k = t & 255;
    float v = (k < 128) ? W1l[k * 128 + m] : W1r[(k - 128) * 128 + m];
    WT1[t] = f2bf(v);
  } else {
    int i = t - 128 * 256;
    if (i < 64 * 256) {
      int m = i >> 8, k = i & 255;
      float v = (k < 128) ? W2l[k * 64 + m] : W2r[(k - 128) * 64 + m];
      WT2[i] = f2bf(v);
    }
  }
}

// ---- mean aggregation: one wave per node, 16 rows in flight ----
__global__ __launch_bounds__(256) void aggregate(const unsigned* __restrict__ xb,
                                                 const int* __restrict__ cnt,
                                                 const int* __restrict__ buck,
                                                 unsigned* __restrict__ agg) {
  int wid = (blockIdx.x * 256 + threadIdx.x) >> 6;
  int lane = threadIdx.x & 63;
  if (wid >= NN) return;
  int deg = cnt[wid];
  int dcl = min(deg, MAXDEG);
  int slot = buck[(size_t)wid * MAXDEG + lane];   // whole bucket row, coalesced
  float a0 = 0.f, a1 = 0.f;
  for (int p = 0; p < dcl; p += 16) {
    int rem = dcl - p;                            // wave-uniform
    unsigned v[16];
#pragma unroll
    for (int j = 0; j < 16; j++)
      if (j < rem) {
        int s = __shfl(slot, p + j, 64);
        v[j] = xb[(size_t)s * 64 + lane];         // 256B/row coalesced
      }
#pragma unroll
    for (int j = 0; j < 16; j++)
      if (j < rem) { a0 += bflo(v[j]); a1 += bfhi(v[j]); }
  }
  float inv = 1.f / (float)max(deg, 1);
  a0 *= inv; a1 *= inv;
  agg[(size_t)wid * 64 + lane] = ((unsigned)f2bf(a1) << 16) | f2bf(a0);
}

// ---- MFMA GEMM: out = relu?( [agg|x] (64xK=256) @ W (256xM) + b ) ----
// 256 thr = 4 waves; 64 nodes/block; A staged in LDS; B from k-major WT (L2-hot).
// Epilogue: C-tile restaged through wave-private sA rows -> full-line uint4 stores.
template <int M, bool RELU, typename OutT>
__global__ __launch_bounds__(256) void sage_gemm(const unsigned* __restrict__ agg,
                                                 const unsigned* __restrict__ xb,
                                                 const unsigned short* __restrict__ WT,
                                                 const float* __restrict__ bias,
                                                 OutT* __restrict__ out) {
  constexpr int LDA = 264;                       // +8 bf16 pad; 528B pitch
  __shared__ unsigned short sA[64][LDA];

  const int t = threadIdx.x;
  const int node0 = blockIdx.x * 64;

  // stage A: row = [agg(128bf16)=16 uint4 | x(128bf16)=16 uint4]
  for (int i = t; i < 64 * 32; i += 256) {
    int row = i >> 5, c = i & 31;
    int node = node0 + row;
    uint4 v = {0u, 0u, 0u, 0u};
    if (node < NN)
      v = (c < 16) ? ((const uint4*)(agg + (size_t)node * 64))[c]
                   : ((const uint4*)(xb + (size_t)node * 64))[c - 16];
    *(uint4*)&sA[row][c * 8] = v;
  }
  __syncthreads();

  const int lane = t & 63;
  const int wv = t >> 6;        // 16-node sub-tile per wave
  const int m = lane & 15;
  const int q = lane >> 4;

  f32x4 acc[M / 16];
#pragma unroll
  for (int c = 0; c < M / 16; c++) acc[c] = {0.f, 0.f, 0.f, 0.f};

#pragma unroll
  for (int ks = 0; ks < 8; ks++) {
    short8 a = *(const short8*)&sA[wv * 16 + m][ks * 32 + q * 8];   // A[m][q*8+j]
#pragma unroll
    for (int c = 0; c < M / 16; c++) {
      // B[k=q*8+j][n=c*16+m] = WT[n][k], contiguous 16B in k
      short8 b = *(const short8*)(WT + (size_t)(c * 16 + m) * 256 + ks * 32 + q * 8);
      acc[c] = __builtin_amdgcn_mfma_f32_16x16x32_bf16(a, b, acc[c], 0, 0, 0);
    }
  }

  // ---- epilogue: stage into own wave's dead sA rows (wave-private, no barrier),
  // then coalesced full-line copies out.
#pragma unroll
  for (int c = 0; c < M / 16; c++) {
    int col = c * 16 + m;
    float bc = bias[col];
#pragma unroll
    for (int r = 0; r < 4; r++) {
      int lr = wv * 16 + q * 4 + r;               // D[row=q*4+r][col=m]
      float v = acc[c][r] + bc;
      if (RELU) v = fmaxf(v, 0.f);
      if constexpr (sizeof(OutT) == 2) sA[lr][col] = f2bf(v);
      else ((float*)&sA[lr][0])[col] = v;
    }
  }
  // row payload = 256B both cases (128 bf16 or 64 f32) = 16 uint4 chunks
#pragma unroll
  for (int it = 0; it < 4; it++) {
    int idx = it * 64 + lane;                     // 16 rows x 16 chunks
    int rr = idx >> 4, cc = idx & 15;
    int node = node0 + wv * 16 + rr;
    if (node < NN) {
      uint4 v = *(const uint4*)((const char*)&sA[wv * 16 + rr][0] + cc * 16);
      *(uint4*)((char*)(out + (size_t)node * M) + cc * 16) = v;
    }
  }
}

extern "C" void kernel_launch(void* const* d_in, const int* in_sizes, int n_in,
                              void* d_out, int out_size, void* d_ws, size_t ws_size,
                              hipStream_t stream) {
  const float* x   = (const float*)d_in[0];
  const int*   ei  = (const int*)d_in[1];
  const float* W1l = (const float*)d_in[2];
  const float* b1  = (const float*)d_in[3];
  const float* W1r = (const float*)d_in[4];
  const float* W2l = (const float*)d_in[5];
  const float* b2  = (const float*)d_in[6];
  const float* W2r = (const float*)d_in[7];
  float* out = (float*)d_out;

  // ws: cnt 0.5MB | buck 25.6MB | xbf 12.8MB | agg 12.8MB | h 12.8MB | WT1 | WT2
  char* ws = (char*)d_ws;
  int* cnt  = (int*)ws;                                   ws += (512 << 10);
  int* buck = (int*)ws;                                   ws += (size_t)NN * MAXDEG * 4;
  unsigned* xbf = (unsigned*)ws;                          ws += (size_t)NN * 64 * 4;
  unsigned* aggb = (unsigned*)ws;                         ws += (size_t)NN * 64 * 4;
  unsigned* hb = (unsigned*)ws;                           ws += (size_t)NN * 64 * 4;
  unsigned short* WT1 = (unsigned short*)ws;              ws += 128 * 256 * 2;
  unsigned short* WT2 = (unsigned short*)ws;              ws += 64 * 256 * 2;

  const int* src = ei;        // edge_index[0]
  const int* dst = ei + NE;   // edge_index[1]

  hipMemsetAsync(cnt, 0, (size_t)NN * 4, stream);
  build_buckets<<<NSLICE * (NE / CHUNK), 256, 0, stream>>>(src, dst, cnt, buck);
  to_bf16<<<(NN * 32 + 255) / 256, 256, 0, stream>>>(x, xbf);
  transpose_w<<<192, 256, 0, stream>>>(W1l, W1r, W2l, W2r, WT1, WT2);

  // layer 1: h = relu([mean|x] @ [W1l;W1r] + b1), bf16
  aggregate<<<(NN * 64 + 255) / 256, 256, 0, stream>>>(xbf, cnt, buck, aggb);
  sage_gemm<128, true, unsigned short><<<(NN + 63) / 64, 256, 0, stream>>>(
      aggb, xbf, WT1, b1, (unsigned short*)hb);

  // layer 2: out = [mean|h] @ [W2l;W2r] + b2, f32
  aggregate<<<(NN * 64 + 255) / 256, 256, 0, stream>>>(hb, cnt, buck, aggb);
  sage_gemm<64, false, float><<<(NN + 63) / 64, 256, 0, stream>>>(
      aggb, hb, WT2, b2, out);
}

// Round 8
// 398.236 us; speedup vs baseline: 3.4751x; 1.2079x over previous
//
#include <hip/hip_runtime.h>
#include <stdint.h>

#define NN 100000      // nodes
#define NE 1600000     // edges
#define MAXDEG 64      // Poisson(16): P(deg>64) ~ 1e-19, safe cap
#define NSLICE 8       // XCD count; slice = blockIdx & 7 (perf heuristic only)
#define SLICE_SZ 12500 // nodes per slice
#define CHUNK 6400     // edges per block; NE/CHUNK = 250 chunks per slice

typedef __attribute__((ext_vector_type(8))) short short8;
typedef __attribute__((ext_vector_type(4))) float f32x4;

__device__ __forceinline__ float bflo(unsigned v) { return __uint_as_float(v << 16); }
__device__ __forceinline__ float bfhi(unsigned v) { return __uint_as_float(v & 0xffff0000u); }
__device__ __forceinline__ unsigned short f2bf(float f) {   // round-to-nearest-even
  unsigned u = __float_as_uint(f);
  u += 0x7fff + ((u >> 16) & 1);
  return (unsigned short)(u >> 16);
}

// ---- XCD-sliced bucket build: per-XCD write region 3.2MB -> L2-resident ----
__global__ __launch_bounds__(256) void build_buckets(const int* __restrict__ src,
                                                     const int* __restrict__ dst,
                                                     int* __restrict__ cnt,
                                                     int* __restrict__ buck) {
  const int slice = blockIdx.x & (NSLICE - 1);
  const int chunk = blockIdx.x >> 3;
  const int c0 = chunk * CHUNK;
  const int lo = slice * SLICE_SZ, hi = lo + SLICE_SZ;
  for (int e = c0 + (int)threadIdx.x * 4; e < c0 + CHUNK; e += 1024) {
    int4 d = *(const int4*)(dst + e);
    int4 s = *(const int4*)(src + e);
    if (d.x >= lo && d.x < hi) { int p = atomicAdd(&cnt[d.x], 1); if (p < MAXDEG) buck[d.x * MAXDEG + p] = s.x; }
    if (d.y >= lo && d.y < hi) { int p = atomicAdd(&cnt[d.y], 1); if (p < MAXDEG) buck[d.y * MAXDEG + p] = s.y; }
    if (d.z >= lo && d.z < hi) { int p = atomicAdd(&cnt[d.z], 1); if (p < MAXDEG) buck[d.z * MAXDEG + p] = s.z; }
    if (d.w >= lo && d.w < hi) { int p = atomicAdd(&cnt[d.w], 1); if (p < MAXDEG) buck[d.w * MAXDEG + p] = s.w; }
  }
}

// ---- f32 -> packed bf16x2 (float4 per thread) ----
__global__ __launch_bounds__(256) void to_bf16(const float* __restrict__ x,
                                               unsigned* __restrict__ xb) {
  int i = blockIdx.x * 256 + threadIdx.x;     // over NN*32
  if (i >= NN * 32) return;
  float4 v = ((const float4*)x)[i];
  uint2 o;
  o.x = ((unsigned)f2bf(v.y) << 16) | f2bf(v.x);
  o.y = ((unsigned)f2bf(v.w) << 16) | f2bf(v.z);
  ((uint2*)xb)[i] = o;
}

// ---- one-time W transpose -> k-major bf16: WT[m][k], k = [Wl rows | Wr rows] ----
__global__ __launch_bounds__(256) void transpose_w(const float* __restrict__ W1l,
                                                   const float* __restrict__ W1r,
                                                   const float* __restrict__ W2l,
                                                   const float* __restrict__ W2r,
                                                   unsigned short* __restrict__ WT1,
                                                   unsigned short* __restrict__ WT2) {
  int t = blockIdx.x * 256 + threadIdx.x;
  if (t < 128 * 256) {
    int m = t >> 8, k = t & 255;
    float v = (k < 128) ? W1l[k * 128 + m] : W1r[(k - 128) * 128 + m];
    WT1[t] = f2bf(v);
  } else {
    int i = t - 128 * 256;
    if (i < 64 * 256) {
      int m = i >> 8, k = i & 255;
      float v = (k < 128) ? W2l[k * 64 + m] : W2r[(k - 128) * 64 + m];
      WT2[i] = f2bf(v);
    }
  }
}

// ---- mean aggregation: one wave per node. Loads are UNCONDITIONAL within a
// 16-batch (shuffle index clamped to last valid slot -> duplicate rows are
// L1-hot) so the compiler keeps all 16 in flight; mask applied at accumulate.
__global__ __launch_bounds__(256) void aggregate(const unsigned* __restrict__ xb,
                                                 const int* __restrict__ cnt,
                                                 const int* __restrict__ buck,
                                                 unsigned* __restrict__ agg) {
  int wid = (blockIdx.x * 256 + threadIdx.x) >> 6;
  int lane = threadIdx.x & 63;
  if (wid >= NN) return;
  int deg = cnt[wid];
  int dcl = min(deg, MAXDEG);
  int slot = buck[(size_t)wid * MAXDEG + lane];   // whole bucket row, coalesced
  float a0 = 0.f, a1 = 0.f;
  if (dcl > 0) {                                  // wave-uniform
    int last = dcl - 1;
    for (int p = 0; p < dcl; p += 16) {
      unsigned v[16];
#pragma unroll
      for (int j = 0; j < 16; j++) {
        int s = __shfl(slot, min(p + j, last), 64);
        v[j] = xb[(size_t)s * 64 + lane];         // 256B/row coalesced, no branch
      }
#pragma unroll
      for (int j = 0; j < 16; j++) {
        unsigned vj = (p + j <= last) ? v[j] : 0u;   // v_cndmask
        a0 += bflo(vj); a1 += bfhi(vj);
      }
    }
  }
  float inv = 1.f / (float)max(deg, 1);
  a0 *= inv; a1 *= inv;
  agg[(size_t)wid * 64 + lane] = ((unsigned)f2bf(a1) << 16) | f2bf(a0);
}

// ---- MFMA GEMM: out = relu?( [agg|x] (64xK=256) @ W (256xM) + b ) ----
template <int M, bool RELU, typename OutT>
__global__ __launch_bounds__(256) void sage_gemm(const unsigned* __restrict__ agg,
                                                 const unsigned* __restrict__ xb,
                                                 const unsigned short* __restrict__ WT,
                                                 const float* __restrict__ bias,
                                                 OutT* __restrict__ out) {
  constexpr int LDA = 264;                       // +8 bf16 pad; 528B pitch
  __shared__ unsigned short sA[64][LDA];

  const int t = threadIdx.x;
  const int node0 = blockIdx.x * 64;

  // stage A: row = [agg(128bf16)=16 uint4 | x(128bf16)=16 uint4]
  for (int i = t; i < 64 * 32; i += 256) {
    int row = i >> 5, c = i & 31;
    int node = node0 + row;
    uint4 v = {0u, 0u, 0u, 0u};
    if (node < NN)
      v = (c < 16) ? ((const uint4*)(agg + (size_t)node * 64))[c]
                   : ((const uint4*)(xb + (size_t)node * 64))[c - 16];
    *(uint4*)&sA[row][c * 8] = v;
  }
  __syncthreads();

  const int lane = t & 63;
  const int wv = t >> 6;        // 16-node sub-tile per wave
  const int m = lane & 15;
  const int q = lane >> 4;

  f32x4 acc[M / 16];
#pragma unroll
  for (int c = 0; c < M / 16; c++) acc[c] = {0.f, 0.f, 0.f, 0.f};

#pragma unroll
  for (int ks = 0; ks < 8; ks++) {
    short8 a = *(const short8*)&sA[wv * 16 + m][ks * 32 + q * 8];   // A[m][q*8+j]
#pragma unroll
    for (int c = 0; c < M / 16; c++) {
      // B[k=q*8+j][n=c*16+m] = WT[n][k], contiguous 16B in k
      short8 b = *(const short8*)(WT + (size_t)(c * 16 + m) * 256 + ks * 32 + q * 8);
      acc[c] = __builtin_amdgcn_mfma_f32_16x16x32_bf16(a, b, acc[c], 0, 0, 0);
    }
  }

  // epilogue: stage into own wave's dead sA rows (wave-private), then
  // coalesced full-line copies out.
#pragma unroll
  for (int c = 0; c < M / 16; c++) {
    int col = c * 16 + m;
    float bc = bias[col];
#pragma unroll
    for (int r = 0; r < 4; r++) {
      int lr = wv * 16 + q * 4 + r;               // D[row=q*4+r][col=m]
      float v = acc[c][r] + bc;
      if (RELU) v = fmaxf(v, 0.f);
      if constexpr (sizeof(OutT) == 2) sA[lr][col] = f2bf(v);
      else ((float*)&sA[lr][0])[col] = v;
    }
  }
#pragma unroll
  for (int it = 0; it < 4; it++) {
    int idx = it * 64 + lane;                     // 16 rows x 16 chunks of 16B
    int rr = idx >> 4, cc = idx & 15;
    int node = node0 + wv * 16 + rr;
    if (node < NN) {
      uint4 v = *(const uint4*)((const char*)&sA[wv * 16 + rr][0] + cc * 16);
      *(uint4*)((char*)(out + (size_t)node * M) + cc * 16) = v;
    }
  }
}

extern "C" void kernel_launch(void* const* d_in, const int* in_sizes, int n_in,
                              void* d_out, int out_size, void* d_ws, size_t ws_size,
                              hipStream_t stream) {
  const float* x   = (const float*)d_in[0];
  const int*   ei  = (const int*)d_in[1];
  const float* W1l = (const float*)d_in[2];
  const float* b1  = (const float*)d_in[3];
  const float* W1r = (const float*)d_in[4];
  const float* W2l = (const float*)d_in[5];
  const float* b2  = (const float*)d_in[6];
  const float* W2r = (const float*)d_in[7];
  float* out = (float*)d_out;

  // ws: cnt 0.5MB | buck 25.6MB | xbf 12.8MB | agg 12.8MB | h 12.8MB | WT1 | WT2
  char* ws = (char*)d_ws;
  int* cnt  = (int*)ws;                                   ws += (512 << 10);
  int* buck = (int*)ws;                                   ws += (size_t)NN * MAXDEG * 4;
  unsigned* xbf = (unsigned*)ws;                          ws += (size_t)NN * 64 * 4;
  unsigned* aggb = (unsigned*)ws;                         ws += (size_t)NN * 64 * 4;
  unsigned* hb = (unsigned*)ws;                           ws += (size_t)NN * 64 * 4;
  unsigned short* WT1 = (unsigned short*)ws;              ws += 128 * 256 * 2;
  unsigned short* WT2 = (unsigned short*)ws;              ws += 64 * 256 * 2;

  const int* src = ei;        // edge_index[0]
  const int* dst = ei + NE;   // edge_index[1]

  hipMemsetAsync(cnt, 0, (size_t)NN * 4, stream);
  build_buckets<<<NSLICE * (NE / CHUNK), 256, 0, stream>>>(src, dst, cnt, buck);
  to_bf16<<<(NN * 32 + 255) / 256, 256, 0, stream>>>(x, xbf);
  transpose_w<<<192, 256, 0, stream>>>(W1l, W1r, W2l, W2r, WT1, WT2);

  // layer 1: h = relu([mean|x] @ [W1l;W1r] + b1), bf16
  aggregate<<<(NN * 64 + 255) / 256, 256, 0, stream>>>(xbf, cnt, buck, aggb);
  sage_gemm<128, true, unsigned short><<<(NN + 63) / 64, 256, 0, stream>>>(
      aggb, xbf, WT1, b1, (unsigned short*)hb);

  // layer 2: out = [mean|h] @ [W2l;W2r] + b2, f32
  aggregate<<<(NN * 64 + 255) / 256, 256, 0, stream>>>(hb, cnt, buck, aggb);
  sage_gemm<64, false, float><<<(NN + 63) / 64, 256, 0, stream>>>(
      aggb, hb, WT2, b2, out);
}

// Round 9
// 378.336 us; speedup vs baseline: 3.6578x; 1.0526x over previous
//
#include <hip/hip_runtime.h>
#include <stdint.h>

#define NN 100000      // nodes
#define NE 1600000     // edges
#define MAXDEG 64      // Poisson(16): P(deg>64) ~ 1e-19, safe cap
#define NSLICE 8       // XCD count; slice = blockIdx & 7 (perf heuristic only)
#define SLICE_SZ 12500 // nodes per slice
#define CHUNK 6400     // edges per block; NE/CHUNK = 250 chunks per slice

typedef __attribute__((ext_vector_type(8))) short short8;
typedef __attribute__((ext_vector_type(4))) float f32x4;

__device__ __forceinline__ float bflo(unsigned v) { return __uint_as_float(v << 16); }
__device__ __forceinline__ float bfhi(unsigned v) { return __uint_as_float(v & 0xffff0000u); }
__device__ __forceinline__ unsigned short f2bf(float f) {   // round-to-nearest-even
  unsigned u = __float_as_uint(f);
  u += 0x7fff + ((u >> 16) & 1);
  return (unsigned short)(u >> 16);
}

// ---- XCD-sliced bucket build: per-XCD write region 3.2MB -> L2-resident ----
__global__ __launch_bounds__(256) void build_buckets(const int* __restrict__ src,
                                                     const int* __restrict__ dst,
                                                     int* __restrict__ cnt,
                                                     int* __restrict__ buck) {
  const int slice = blockIdx.x & (NSLICE - 1);
  const int chunk = blockIdx.x >> 3;
  const int c0 = chunk * CHUNK;
  const int lo = slice * SLICE_SZ, hi = lo + SLICE_SZ;
  for (int e = c0 + (int)threadIdx.x * 4; e < c0 + CHUNK; e += 1024) {
    int4 d = *(const int4*)(dst + e);
    int4 s = *(const int4*)(src + e);
    if (d.x >= lo && d.x < hi) { int p = atomicAdd(&cnt[d.x], 1); if (p < MAXDEG) buck[d.x * MAXDEG + p] = s.x; }
    if (d.y >= lo && d.y < hi) { int p = atomicAdd(&cnt[d.y], 1); if (p < MAXDEG) buck[d.y * MAXDEG + p] = s.y; }
    if (d.z >= lo && d.z < hi) { int p = atomicAdd(&cnt[d.z], 1); if (p < MAXDEG) buck[d.z * MAXDEG + p] = s.z; }
    if (d.w >= lo && d.w < hi) { int p = atomicAdd(&cnt[d.w], 1); if (p < MAXDEG) buck[d.w * MAXDEG + p] = s.w; }
  }
}

// ---- f32 -> packed bf16x2 (float4 per thread) ----
__global__ __launch_bounds__(256) void to_bf16(const float* __restrict__ x,
                                               unsigned* __restrict__ xb) {
  int i = blockIdx.x * 256 + threadIdx.x;     // over NN*32
  if (i >= NN * 32) return;
  float4 v = ((const float4*)x)[i];
  uint2 o;
  o.x = ((unsigned)f2bf(v.y) << 16) | f2bf(v.x);
  o.y = ((unsigned)f2bf(v.w) << 16) | f2bf(v.z);
  ((uint2*)xb)[i] = o;
}

// ---- one-time W transpose -> k-major bf16: WT[m][k], k = [Wl rows | Wr rows] ----
__global__ __launch_bounds__(256) void transpose_w(const float* __restrict__ W1l,
                                                   const float* __restrict__ W1r,
                                                   const float* __restrict__ W2l,
                                                   const float* __restrict__ W2r,
                                                   unsigned short* __restrict__ WT1,
                                                   unsigned short* __restrict__ WT2) {
  int t = blockIdx.x * 256 + threadIdx.x;
  if (t < 128 * 256) {
    int m = t >> 8, k = t & 255;
    float v = (k < 128) ? W1l[k * 128 + m] : W1r[(k - 128) * 128 + m];
    WT1[t] = f2bf(v);
  } else {
    int i = t - 128 * 256;
    if (i < 64 * 256) {
      int m = i >> 8, k = i & 255;
      float v = (k < 128) ? W2l[k * 64 + m] : W2r[(k - 128) * 64 + m];
      WT2[i] = f2bf(v);
    }
  }
}

// ---- FUSED layer: gather-mean directly into LDS, then MFMA. BARRIER-FREE:
// wave wv owns sA rows [wv*16, wv*16+16) exclusively (writes them in the
// gather phase, reads them as A-fragments and epilogue staging). Per-wave DS
// ordering makes write->read safe without __syncthreads.
template <int M, bool RELU, typename OutT>
__global__ __launch_bounds__(256) void sage_fused(const unsigned* __restrict__ xb,
                                                  const int* __restrict__ cnt,
                                                  const int* __restrict__ buck,
                                                  const unsigned short* __restrict__ WT,
                                                  const float* __restrict__ bias,
                                                  OutT* __restrict__ out) {
  constexpr int LDA = 264;                       // +8 bf16 pad; 528B pitch
  __shared__ unsigned short sA[64][LDA];

  const int t = threadIdx.x;
  const int lane = t & 63;
  const int wv = t >> 6;
  const int node0 = blockIdx.x * 64;
  const int nb = node0 + wv * 16;                // this wave's 16 nodes

  // ---- prefetch: 16 bucket rows + 16 x rows + 16 degrees (all independent) ----
  int slot[16]; unsigned xr[16]; int deg[16];
#pragma unroll
  for (int i = 0; i < 16; i++) {
    int node = nb + i;
    if (node < NN) {                             // lane-uniform branch
      slot[i] = buck[(size_t)node * MAXDEG + lane];
      xr[i]   = xb[(size_t)node * 64 + lane];
      deg[i]  = cnt[node];
    } else { slot[i] = 0; xr[i] = 0u; deg[i] = 0; }
  }

  // ---- gather-mean each of my 16 rows into wave-private LDS ----
#pragma unroll
  for (int i = 0; i < 16; i++) {
    float a0 = 0.f, a1 = 0.f;
    int dcl = min(deg[i], MAXDEG);
    if (dcl > 0) {                               // wave-uniform
      int last = dcl - 1;
      for (int p = 0; p < dcl; p += 16) {
        unsigned v[16];
#pragma unroll
        for (int j = 0; j < 16; j++) {
          int s = __shfl(slot[i], min(p + j, last), 64);
          v[j] = xb[(size_t)s * 64 + lane];      // 256B/row coalesced, no branch
        }
#pragma unroll
        for (int j = 0; j < 16; j++) {
          unsigned vj = (p + j <= last) ? v[j] : 0u;
          a0 += bflo(vj); a1 += bfhi(vj);
        }
      }
    }
    float inv = 1.f / (float)max(deg[i], 1);
    unsigned pk = ((unsigned)f2bf(a1 * inv) << 16) | f2bf(a0 * inv);
    ((unsigned*)&sA[wv * 16 + i][0])[lane]   = pk;      // agg half: k in [0,128)
    ((unsigned*)&sA[wv * 16 + i][128])[lane] = xr[i];   // x half:   k in [128,256)
  }

  // ---- MFMA: A from my LDS rows, B from k-major WT in global (L2-hot) ----
  const int m = lane & 15;
  const int q = lane >> 4;

  f32x4 acc[M / 16];
#pragma unroll
  for (int c = 0; c < M / 16; c++) acc[c] = {0.f, 0.f, 0.f, 0.f};

#pragma unroll
  for (int ks = 0; ks < 8; ks++) {
    short8 a = *(const short8*)&sA[wv * 16 + m][ks * 32 + q * 8];   // A[m][q*8+j]
#pragma unroll
    for (int c = 0; c < M / 16; c++) {
      // B[k=q*8+j][n=c*16+m] = WT[n][k], contiguous 16B in k
      short8 b = *(const short8*)(WT + (size_t)(c * 16 + m) * 256 + ks * 32 + q * 8);
      acc[c] = __builtin_amdgcn_mfma_f32_16x16x32_bf16(a, b, acc[c], 0, 0, 0);
    }
  }

  // ---- epilogue: restage C through my (dead) sA rows -> full-line stores ----
#pragma unroll
  for (int c = 0; c < M / 16; c++) {
    int col = c * 16 + m;
    float bc = bias[col];
#pragma unroll
    for (int r = 0; r < 4; r++) {
      int lr = wv * 16 + q * 4 + r;               // D[row=q*4+r][col=m]
      float v = acc[c][r] + bc;
      if (RELU) v = fmaxf(v, 0.f);
      if constexpr (sizeof(OutT) == 2) sA[lr][col] = f2bf(v);
      else ((float*)&sA[lr][0])[col] = v;
    }
  }
#pragma unroll
  for (int it = 0; it < 4; it++) {
    int idx = it * 64 + lane;                     // 16 rows x 16 chunks of 16B
    int rr = idx >> 4, cc = idx & 15;
    int node = node0 + wv * 16 + rr;
    if (node < NN) {
      uint4 v = *(const uint4*)((const char*)&sA[wv * 16 + rr][0] + cc * 16);
      *(uint4*)((char*)(out + (size_t)node * M) + cc * 16) = v;
    }
  }
}

extern "C" void kernel_launch(void* const* d_in, const int* in_sizes, int n_in,
                              void* d_out, int out_size, void* d_ws, size_t ws_size,
                              hipStream_t stream) {
  const float* x   = (const float*)d_in[0];
  const int*   ei  = (const int*)d_in[1];
  const float* W1l = (const float*)d_in[2];
  const float* b1  = (const float*)d_in[3];
  const float* W1r = (const float*)d_in[4];
  const float* W2l = (const float*)d_in[5];
  const float* b2  = (const float*)d_in[6];
  const float* W2r = (const float*)d_in[7];
  float* out = (float*)d_out;

  // ws: cnt 0.5MB | buck 25.6MB | xbf 12.8MB | h 12.8MB | WT1 | WT2
  char* ws = (char*)d_ws;
  int* cnt  = (int*)ws;                                   ws += (512 << 10);
  int* buck = (int*)ws;                                   ws += (size_t)NN * MAXDEG * 4;
  unsigned* xbf = (unsigned*)ws;                          ws += (size_t)NN * 64 * 4;
  unsigned* hb = (unsigned*)ws;                           ws += (size_t)NN * 64 * 4;
  unsigned short* WT1 = (unsigned short*)ws;              ws += 128 * 256 * 2;
  unsigned short* WT2 = (unsigned short*)ws;              ws += 64 * 256 * 2;

  const int* src = ei;        // edge_index[0]
  const int* dst = ei + NE;   // edge_index[1]

  hipMemsetAsync(cnt, 0, (size_t)NN * 4, stream);
  build_buckets<<<NSLICE * (NE / CHUNK), 256, 0, stream>>>(src, dst, cnt, buck);
  to_bf16<<<(NN * 32 + 255) / 256, 256, 0, stream>>>(x, xbf);
  transpose_w<<<192, 256, 0, stream>>>(W1l, W1r, W2l, W2r, WT1, WT2);

  // layer 1: h = relu([mean|x] @ [W1l;W1r] + b1), bf16
  sage_fused<128, true, unsigned short><<<(NN + 63) / 64, 256, 0, stream>>>(
      xbf, cnt, buck, WT1, b1, (unsigned short*)hb);

  // layer 2: out = [mean|h] @ [W2l;W2r] + b2, f32
  sage_fused<64, false, float><<<(NN + 63) / 64, 256, 0, stream>>>(
      hb, cnt, buck, WT2, b2, out);
}